// Round 2
// baseline (2217.370 us; speedup 1.0000x reference)
//
#include <hip/hip_runtime.h>
#include <stdint.h>

// ---------------------------------------------------------------------------
// GaussianVectorQuantizer (training path) for MI355X.
// Outputs (flat f32): zq[32*256*256] | precision_q[1] | prob[32*256*512] | log_prob[32*256*512]
//
// RNG schemes (template S):
//   0: jax_threefry_partitionable (DEFAULT modern JAX): fold-like split
//      (subkey i = both output words of tf(key, (0,i))) + 32-bit draws =
//      o0 ^ o1 of tf(key, (0, flat_index)).
//   3: original scheme: split via iota(2*num) halves; draws via iota(size)
//      halves pairing (i, i+half), word by half.
// ---------------------------------------------------------------------------

#define TOTAL_CPROB 320u        // 32*10
#define TOTAL_SPLIT 4u

__device__ __forceinline__ uint32_t rotl32(uint32_t x, int r){ return (x << r) | (x >> (32 - r)); }

__device__ __forceinline__ void tf2x32(uint32_t k0, uint32_t k1, uint32_t x0, uint32_t x1,
                                       uint32_t &o0, uint32_t &o1){
  uint32_t k2 = k0 ^ k1 ^ 0x1BD11BDAu;
  x0 += k0; x1 += k1;
#define TFR(r) { x0 += x1; x1 = rotl32(x1,(r)); x1 ^= x0; }
  TFR(13) TFR(15) TFR(26) TFR(6)
  x0 += k1; x1 += k2 + 1u;
  TFR(17) TFR(29) TFR(16) TFR(24)
  x0 += k2; x1 += k0 + 2u;
  TFR(13) TFR(15) TFR(26) TFR(6)
  x0 += k0; x1 += k1 + 3u;
  TFR(17) TFR(29) TFR(16) TFR(24)
  x0 += k1; x1 += k2 + 4u;
  TFR(13) TFR(15) TFR(26) TFR(6)
  x0 += k2; x1 += k0 + 5u;
#undef TFR
  o0 = x0; o1 = x1;
}

// 32-bit random draw at flat index i of an array with `total` elements.
template<int S>
__device__ __forceinline__ uint32_t rbits(uint32_t k0, uint32_t k1, uint32_t i, uint32_t total){
  uint32_t o0, o1;
  if (S == 0){                       // partitionable: ctr=(0,i), xor-fold
    tf2x32(k0, k1, 0u, i, o0, o1); return o0 ^ o1;
  } else if (S == 1){                // partitionable variant: word 0
    tf2x32(k0, k1, 0u, i, o0, o1); return o0;
  } else if (S == 2){                // partitionable variant: word 1
    tf2x32(k0, k1, 0u, i, o0, o1); return o1;
  } else {                           // original: iota halves pairing
    uint32_t half = total >> 1;
    if (i < half){ tf2x32(k0, k1, i, i + half, o0, o1); return o0; }
    else         { tf2x32(k0, k1, i - half, i, o0, o1); return o1; }
  }
}

template<int S>
__device__ __forceinline__ void derive_keys(uint32_t &kc0, uint32_t &kc1,
                                            uint32_t &ke0, uint32_t &ke1){
  // key(42) = (0,42); kc, ke = split(key)
  if (S == 3){
    // original split: counts=iota(4), halves pairing -> out[i]; keys = reshape(2,2)
    uint32_t a0,a1,b0,b1;
    tf2x32(0u,42u, 0u,2u, a0,a1);    // pair (0,2): out0=a0, out2=a1
    tf2x32(0u,42u, 1u,3u, b0,b1);    // pair (1,3): out1=b0, out3=b1
    kc0=a0; kc1=b0; ke0=a1; ke1=b1;
  } else {
    // fold-like split: key_i = (o0,o1) of tf(key, (0,i))
    tf2x32(0u,42u, 0u,0u, kc0,kc1);
    tf2x32(0u,42u, 0u,1u, ke0,ke1);
  }
}

__device__ __forceinline__ float bits_to_u01(uint32_t b){
  return __uint_as_float((b >> 9) | 0x3F800000u) - 1.0f;   // [0,1), matches jax
}
__device__ __forceinline__ float gumbel_u(float u){
  return -__logf(-__logf(u + 1e-10f) + 1e-10f);
}

// ws layout (floats): cprob_zq @0 (320) | cprob_pr @384 (320) | bk2 @1024 (5120) | M @8192 (4194304)

// ---------------------------------------------------------------------------
// K1: precision_q + both c_prob copies (t<32 -> slot0/zq, t>=32 -> slot1/prob)
// ---------------------------------------------------------------------------
template<int S0, int S1>
__global__ void k_cprob(const float* __restrict__ c_logits,
                        const float* __restrict__ lpq,
                        const float* __restrict__ lpqc,
                        float* __restrict__ ws, float* __restrict__ out){
  int t = threadIdx.x;
  if (t == 0) out[2097152] = 0.5f / fmaxf(1.0f + __expf(lpq[0]), 1e-10f);
  float pqc = 0.5f / fmaxf(1.0f + __expf(lpqc[0]), 1e-10f);
  int b = t & 31;
  int which = t >> 5;
  uint32_t kc0, kc1, ke0, ke1;
  if (which == 0) derive_keys<S0>(kc0, kc1, ke0, ke1);
  else            derive_keys<S1>(kc0, kc1, ke0, ke1);
  (void)ke0; (void)ke1;
  float y[10]; float mx = -1e30f;
  #pragma unroll
  for (int c = 0; c < 10; ++c){
    uint32_t i = (uint32_t)(b * 10 + c);
    uint32_t bits = (which == 0) ? rbits<S0>(kc0, kc1, i, TOTAL_CPROB)
                                 : rbits<S1>(kc0, kc1, i, TOTAL_CPROB);
    float g = gumbel_u(bits_to_u01(bits));
    float v = (c_logits[b * 10 + c] * pqc + g) * 2.0f;   // /T, T=0.5
    y[c] = v; mx = fmaxf(mx, v);
  }
  float s = 0.f;
  #pragma unroll
  for (int c = 0; c < 10; ++c){ y[c] = __expf(y[c] - mx); s += y[c]; }
  float inv = 1.0f / s;
  float* dst = ws + which * 384;
  #pragma unroll
  for (int c = 0; c < 10; ++c) dst[b * 10 + c] = y[c] * inv;
}

// ---------------------------------------------------------------------------
// K2: bk2[c*512+k] = sum_d books^2
// ---------------------------------------------------------------------------
__global__ void k_bk2(const float* __restrict__ books, float* __restrict__ ws){
  int row = blockIdx.x;            // 5120
  int t = threadIdx.x;             // 64
  const float4* p = (const float4*)(books + (size_t)row * 256);
  float4 v = p[t];
  float s = v.x*v.x + v.y*v.y + v.z*v.z + v.w*v.w;
  #pragma unroll
  for (int m = 1; m < 64; m <<= 1) s += __shfl_xor(s, m);
  if (t == 0) ws[1024 + row] = s;
}

// ---------------------------------------------------------------------------
// K3: mixed codebook M[b][k][d] = sum_c cprob_pr[b,c] * books[c,k,d]
// ---------------------------------------------------------------------------
__global__ void k_mix(const float* __restrict__ books, const float* __restrict__ ws,
                      float* __restrict__ M){
  int b = blockIdx.x >> 9, k = blockIdx.x & 511, t = threadIdx.x;   // 64 threads
  float4 acc = make_float4(0.f, 0.f, 0.f, 0.f);
  #pragma unroll
  for (int c = 0; c < 10; ++c){
    float w = ws[384 + b * 10 + c];
    float4 v = ((const float4*)books)[((size_t)(c * 512 + k)) * 64 + t];
    acc.x = fmaf(w, v.x, acc.x); acc.y = fmaf(w, v.y, acc.y);
    acc.z = fmaf(w, v.z, acc.z); acc.w = fmaf(w, v.w, acc.w);
  }
  ((float4*)M)[((size_t)(b * 512 + k)) * 64 + t] = acc;
}

// ---------------------------------------------------------------------------
// K4: prob / log_prob.  16 rows/block, 256 threads, thread (r=t>>4, u=t&15).
// logits (row-shifted) = -pq*(beta[k] - 2*dot(ze, M_b[k])) ; shift cancels in softmax.
// ---------------------------------------------------------------------------
template<int USE_M>
__global__ void __launch_bounds__(256)
k_probs(const float* __restrict__ ze, const float* __restrict__ books,
        const float* __restrict__ M, const float* __restrict__ ws,
        const float* __restrict__ lpq,
        float* __restrict__ prob, float* __restrict__ logp){
  __shared__ float ze_t[16][256];
  __shared__ float m_t[32][256];
  __shared__ float s_l[16][512];
  int B = blockIdx.x, b = B >> 4, n0 = (B & 15) << 4;
  int t = threadIdx.x, r = t >> 4, u = t & 15;
  float pq = 0.5f / fmaxf(1.0f + __expf(lpq[0]), 1e-10f);
  float cp[10];
  #pragma unroll
  for (int c = 0; c < 10; ++c) cp[c] = ws[384 + b * 10 + c];
  const float4* zsrc = (const float4*)(ze + ((size_t)(b * 256 + n0)) * 256);
  for (int q = t; q < 1024; q += 256){
    int rr = q >> 6, d4 = q & 63;
    float4 v = zsrc[q];
    *(float4*)&ze_t[rr][((d4 ^ (rr & 7)) << 2)] = v;
  }
  for (int ci = 0; ci < 16; ++ci){
    __syncthreads();
    int k0 = ci << 5;
    for (int q = t; q < 2048; q += 256){
      int kk = q >> 6, d4 = q & 63;
      float4 v;
      if (USE_M){
        v = ((const float4*)M)[((size_t)(b * 512 + k0 + kk)) * 64 + d4];
      } else {
        v = make_float4(0.f, 0.f, 0.f, 0.f);
        #pragma unroll
        for (int c = 0; c < 10; ++c){
          float4 w = ((const float4*)books)[((size_t)(c * 512 + k0 + kk)) * 64 + d4];
          v.x = fmaf(cp[c], w.x, v.x); v.y = fmaf(cp[c], w.y, v.y);
          v.z = fmaf(cp[c], w.z, v.z); v.w = fmaf(cp[c], w.w, v.w);
        }
      }
      *(float4*)&m_t[kk][((d4 ^ (kk & 7)) << 2)] = v;
    }
    __syncthreads();
    float s0 = 0.f, s1 = 0.f;
    #pragma unroll 8
    for (int d4 = 0; d4 < 64; ++d4){
      float4 z  = *(const float4*)&ze_t[r][((d4 ^ (r & 7)) << 2)];
      float4 a  = *(const float4*)&m_t[u][((d4 ^ (u & 7)) << 2)];
      float4 bb = *(const float4*)&m_t[u + 16][((d4 ^ (u & 7)) << 2)];
      s0 = fmaf(z.x,a.x,s0);  s0 = fmaf(z.y,a.y,s0);  s0 = fmaf(z.z,a.z,s0);  s0 = fmaf(z.w,a.w,s0);
      s1 = fmaf(z.x,bb.x,s1); s1 = fmaf(z.y,bb.y,s1); s1 = fmaf(z.z,bb.z,s1); s1 = fmaf(z.w,bb.w,s1);
    }
    s_l[r][k0 + u]      = s0;
    s_l[r][k0 + 16 + u] = s1;   // each thread reads back only its own writes
  }
  float mx = -1e30f;
  for (int j = 0; j < 32; ++j){
    int k = (j << 4) + u;
    float beta = 0.f;
    #pragma unroll
    for (int c = 0; c < 10; ++c) beta = fmaf(cp[c], ws[1024 + (c << 9) + k], beta);
    float v = -pq * (beta - 2.0f * s_l[r][k]);
    s_l[r][k] = v;
    mx = fmaxf(mx, v);
  }
  #pragma unroll
  for (int mm = 1; mm < 16; mm <<= 1) mx = fmaxf(mx, __shfl_xor(mx, mm));
  float s = 0.f;
  for (int j = 0; j < 32; ++j) s += __expf(s_l[r][(j << 4) + u] - mx);
  #pragma unroll
  for (int mm = 1; mm < 16; mm <<= 1) s += __shfl_xor(s, mm);
  float lse = mx + __logf(s);
  size_t base = ((size_t)(b * 256 + n0 + r)) * 512;
  for (int j = 0; j < 32; ++j){
    int k = (j << 4) + u;
    float lp = s_l[r][k] - lse;
    prob[base + k] = __expf(lp);
    logp[base + k] = lp;
  }
}

// ---------------------------------------------------------------------------
// K5: zq. 32 rows/block (one batch), 256 threads, thread (r=t>>3, u=t&7).
// Per cluster: online-softmax over k-chunks of 32 staged in LDS; weighted PV accum.
// Encoding noise: flat idx = ((b*10+c)*256+n)*512+k into U(32,10,256,512).
// ---------------------------------------------------------------------------
template<int S>
__global__ void __launch_bounds__(256)
k_zq(const float* __restrict__ ze, const float* __restrict__ books,
     const float* __restrict__ ws, const float* __restrict__ lpq,
     float* __restrict__ zq){
  __shared__ float ze_t[32][256];
  __shared__ float b_t[32][256];
  int B = blockIdx.x, b = B >> 3, n0 = (B & 7) << 5;
  int t = threadIdx.x, r = t >> 3, u = t & 7, lane = t & 63;
  float pq = 0.5f / fmaxf(1.0f + __expf(lpq[0]), 1e-10f);
  uint32_t kc0, kc1, ke0, ke1;
  derive_keys<S>(kc0, kc1, ke0, ke1);
  (void)kc0; (void)kc1;
  const float4* zsrc = (const float4*)(ze + ((size_t)(b * 256 + n0)) * 256);
  for (int q = t; q < 2048; q += 256){
    int rr = q >> 6, d4 = q & 63;
    float4 v = zsrc[q];
    *(float4*)&ze_t[rr][((d4 ^ (rr & 7)) << 2)] = v;
  }
  float4 zqa[8];
  #pragma unroll
  for (int mm = 0; mm < 8; ++mm) zqa[mm] = make_float4(0.f, 0.f, 0.f, 0.f);
  int nglob = n0 + r;
  for (int c = 0; c < 10; ++c){
    float cpc = ws[b * 10 + c];
    uint32_t nbase = ((uint32_t)((b * 10 + c) * 256 + nglob)) << 9;
    float m = -1e30f, l = 0.f;
    float4 pz[8];
    #pragma unroll
    for (int mm = 0; mm < 8; ++mm) pz[mm] = make_float4(0.f, 0.f, 0.f, 0.f);
    for (int ci = 0; ci < 16; ++ci){
      __syncthreads();
      const float4* bsrc = (const float4*)(books + ((size_t)(c * 512 + (ci << 5))) * 256);
      for (int q = t; q < 2048; q += 256){
        int kk = q >> 6, d4 = q & 63;
        float4 v = bsrc[q];
        *(float4*)&b_t[kk][((d4 ^ (kk & 7)) << 2)] = v;
      }
      __syncthreads();
      float s0 = 0.f, s1 = 0.f, s2 = 0.f, s3 = 0.f;
      #pragma unroll 8
      for (int d4 = 0; d4 < 64; ++d4){
        float4 z  = *(const float4*)&ze_t[r][((d4 ^ (r & 7)) << 2)];
        float4 b0 = *(const float4*)&b_t[u][((d4 ^ (u & 7)) << 2)];
        float4 b1 = *(const float4*)&b_t[u + 8][((d4 ^ (u & 7)) << 2)];
        float4 b2 = *(const float4*)&b_t[u + 16][((d4 ^ (u & 7)) << 2)];
        float4 b3 = *(const float4*)&b_t[u + 24][((d4 ^ (u & 7)) << 2)];
        s0 = fmaf(z.x,b0.x,s0); s0 = fmaf(z.y,b0.y,s0); s0 = fmaf(z.z,b0.z,s0); s0 = fmaf(z.w,b0.w,s0);
        s1 = fmaf(z.x,b1.x,s1); s1 = fmaf(z.y,b1.y,s1); s1 = fmaf(z.z,b1.z,s1); s1 = fmaf(z.w,b1.w,s1);
        s2 = fmaf(z.x,b2.x,s2); s2 = fmaf(z.y,b2.y,s2); s2 = fmaf(z.z,b2.z,s2); s2 = fmaf(z.w,b2.w,s2);
        s3 = fmaf(z.x,b3.x,s3); s3 = fmaf(z.y,b3.y,s3); s3 = fmaf(z.z,b3.z,s3); s3 = fmaf(z.w,b3.w,s3);
      }
      float ss[4] = {s0, s1, s2, s3};
      float vv[4]; float cm = -1e30f;
      #pragma unroll
      for (int jj = 0; jj < 4; ++jj){
        int kg = (ci << 5) + (jj << 3) + u;
        float bk2v = ws[1024 + (c << 9) + kg];
        uint32_t bits = rbits<S>(ke0, ke1, nbase + (uint32_t)kg, 0u /*total unused for S<3*/);
        float g = gumbel_u(bits_to_u01(bits));
        float v = (-pq * (bk2v - 2.0f * ss[jj]) + g) * 2.0f;   // row-const -pq*ze2 dropped
        vv[jj] = v; cm = fmaxf(cm, v);
      }
      cm = fmaxf(cm, __shfl_xor(cm, 1));
      cm = fmaxf(cm, __shfl_xor(cm, 2));
      cm = fmaxf(cm, __shfl_xor(cm, 4));
      float mn = fmaxf(m, cm);
      float scale = __expf(m - mn);
      float csum = 0.f;
      #pragma unroll
      for (int jj = 0; jj < 4; ++jj){ vv[jj] = __expf(vv[jj] - mn); csum += vv[jj]; }
      csum += __shfl_xor(csum, 1);
      csum += __shfl_xor(csum, 2);
      csum += __shfl_xor(csum, 4);
      l = l * scale + csum;
      m = mn;
      #pragma unroll
      for (int mm = 0; mm < 8; ++mm){
        pz[mm].x *= scale; pz[mm].y *= scale; pz[mm].z *= scale; pz[mm].w *= scale;
      }
      #pragma unroll
      for (int jj = 0; jj < 4; ++jj){
        float pv = vv[jj];
        #pragma unroll
        for (int q2 = 0; q2 < 8; ++q2){
          float wk = __shfl(pv, (lane & 56) | q2, 64);
          int kl = (jj << 3) + q2;
          #pragma unroll
          for (int mm = 0; mm < 8; ++mm){
            float4 bv = *(const float4*)&b_t[kl][(((u + (mm << 3)) ^ (kl & 7)) << 2)];
            pz[mm].x = fmaf(wk, bv.x, pz[mm].x);
            pz[mm].y = fmaf(wk, bv.y, pz[mm].y);
            pz[mm].z = fmaf(wk, bv.z, pz[mm].z);
            pz[mm].w = fmaf(wk, bv.w, pz[mm].w);
          }
        }
      }
    }
    float wc = cpc / l;
    #pragma unroll
    for (int mm = 0; mm < 8; ++mm){
      zqa[mm].x = fmaf(wc, pz[mm].x, zqa[mm].x);
      zqa[mm].y = fmaf(wc, pz[mm].y, zqa[mm].y);
      zqa[mm].z = fmaf(wc, pz[mm].z, zqa[mm].z);
      zqa[mm].w = fmaf(wc, pz[mm].w, zqa[mm].w);
    }
  }
  float* dst = zq + ((size_t)(b * 256 + nglob)) * 256;
  #pragma unroll
  for (int mm = 0; mm < 8; ++mm)
    *(float4*)&dst[(u << 2) + (mm << 5)] = zqa[mm];
}

// ---------------------------------------------------------------------------
extern "C" void kernel_launch(void* const* d_in, const int* in_sizes, int n_in,
                              void* d_out, int out_size, void* d_ws, size_t ws_size,
                              hipStream_t stream){
  (void)in_sizes; (void)n_in; (void)out_size;
  const float* ze    = (const float*)d_in[0];
  const float* cl    = (const float*)d_in[1];
  const float* books = (const float*)d_in[2];
  const float* lpq   = (const float*)d_in[3];
  const float* lpqc  = (const float*)d_in[4];
  float* out  = (float*)d_out;
  float* ws   = (float*)d_ws;
  float* zq   = out;
  float* prob = out + 2097153;
  float* logp = out + 2097153 + 4194304;
  float* M    = ws + 8192;

  // Round 2: corrected partitionable scheme (fold-like split + o0^o1) everywhere.
  // Fallback for Round 3 if this fails: S = 3 (original non-partitionable).
  constexpr int S = 0;

  k_cprob<S, S><<<1, 64, 0, stream>>>(cl, lpq, lpqc, ws, out);
  k_bk2<<<5120, 64, 0, stream>>>(books, ws);
  bool useM = ws_size >= (size_t)(8192 + 4194304) * sizeof(float);
  if (useM){
    k_mix<<<16384, 64, 0, stream>>>(books, ws, M);
    k_probs<1><<<512, 256, 0, stream>>>(ze, books, M, ws, lpq, prob, logp);
  } else {
    k_probs<0><<<512, 256, 0, stream>>>(ze, books, M, ws, lpq, prob, logp);
  }
  k_zq<S><<<256, 256, 0, stream>>>(ze, books, ws, lpq, zq);
}

// Round 3
// 478.813 us; speedup vs baseline: 4.6310x; 4.6310x over previous
//
#include <hip/hip_runtime.h>
#include <stdint.h>

// ---------------------------------------------------------------------------
// GaussianVectorQuantizer (training) MI355X.
// Outputs (flat f32): zq[2097152] | precision_q[1] | prob[4194304] | log_prob[4194304]
// RNG (verified R2): threefry2x32 partitionable, fold-like split, draw = o0^o1.
// R3: k_zq rewritten on mfma_f32_16x16x32_bf16 (flash-style over k, split over c,
//     bf16 partials in ws + combine). Round-2 kernels kept as ws-size fallback.
// ---------------------------------------------------------------------------

typedef __attribute__((ext_vector_type(8))) __bf16 bf16x8;
typedef __attribute__((ext_vector_type(4))) float f32x4;

// ws float-offsets
#define F_BK2    1024
#define F_BKRM   8192
#define F_BKT    663552u      // 8192 + 10*512*256/2
#define F_PART   1318912u     // + 655360
#define F_M      11804672u    // + 32*10*256*256/2
#define F_ENDA   15998976u    // + 4194304 (M)

__device__ __forceinline__ uint32_t rotl32(uint32_t x, int r){ return (x << r) | (x >> (32 - r)); }

__device__ __forceinline__ void tf2x32(uint32_t k0, uint32_t k1, uint32_t x0, uint32_t x1,
                                       uint32_t &o0, uint32_t &o1){
  uint32_t k2 = k0 ^ k1 ^ 0x1BD11BDAu;
  x0 += k0; x1 += k1;
#define TFR(r) { x0 += x1; x1 = rotl32(x1,(r)); x1 ^= x0; }
  TFR(13) TFR(15) TFR(26) TFR(6)
  x0 += k1; x1 += k2 + 1u;
  TFR(17) TFR(29) TFR(16) TFR(24)
  x0 += k2; x1 += k0 + 2u;
  TFR(13) TFR(15) TFR(26) TFR(6)
  x0 += k0; x1 += k1 + 3u;
  TFR(17) TFR(29) TFR(16) TFR(24)
  x0 += k1; x1 += k2 + 4u;
  TFR(13) TFR(15) TFR(26) TFR(6)
  x0 += k2; x1 += k0 + 5u;
#undef TFR
  o0 = x0; o1 = x1;
}

__device__ __forceinline__ uint32_t rbits0(uint32_t k0, uint32_t k1, uint32_t i){
  uint32_t o0, o1; tf2x32(k0, k1, 0u, i, o0, o1); return o0 ^ o1;
}
__device__ __forceinline__ float bits_to_u01(uint32_t b){
  return __uint_as_float((b >> 9) | 0x3F800000u) - 1.0f;
}
__device__ __forceinline__ float gumbel_u(float u){
  return -__logf(-__logf(u + 1e-10f) + 1e-10f);
}
__device__ __forceinline__ float gum_at(uint32_t k0, uint32_t k1, uint32_t idx){
  return gumbel_u(bits_to_u01(rbits0(k0, k1, idx)));
}
__device__ __forceinline__ uint16_t bfbits(float x){
  union { __bf16 h; uint16_t s; } u; u.h = (__bf16)x; return u.s;
}
__device__ __forceinline__ uint32_t pk2(float a, float b){
  return (uint32_t)bfbits(a) | ((uint32_t)bfbits(b) << 16);
}

// ---------------------------------------------------------------------------
// K1: precision_q + c_prob (both slots, scheme 0)
// ---------------------------------------------------------------------------
__global__ void k_cprob(const float* __restrict__ c_logits,
                        const float* __restrict__ lpq,
                        const float* __restrict__ lpqc,
                        float* __restrict__ ws, float* __restrict__ out){
  int t = threadIdx.x;
  if (t == 0) out[2097152] = 0.5f / fmaxf(1.0f + __expf(lpq[0]), 1e-10f);
  float pqc = 0.5f / fmaxf(1.0f + __expf(lpqc[0]), 1e-10f);
  int b = t & 31;
  int which = t >> 5;
  uint32_t kc0, kc1;
  tf2x32(0u, 42u, 0u, 0u, kc0, kc1);   // fold-like split: kc = tf(key,(0,0))
  float y[10]; float mx = -1e30f;
  #pragma unroll
  for (int c = 0; c < 10; ++c){
    float g = gum_at(kc0, kc1, (uint32_t)(b * 10 + c));
    float v = (c_logits[b * 10 + c] * pqc + g) * 2.0f;
    y[c] = v; mx = fmaxf(mx, v);
  }
  float s = 0.f;
  #pragma unroll
  for (int c = 0; c < 10; ++c){ y[c] = __expf(y[c] - mx); s += y[c]; }
  float inv = 1.0f / s;
  float* dst = ws + which * 384;
  #pragma unroll
  for (int c = 0; c < 10; ++c) dst[b * 10 + c] = y[c] * inv;
}

// ---------------------------------------------------------------------------
// K2: bk2[c*512+k] = sum_d books^2
// ---------------------------------------------------------------------------
__global__ void k_bk2(const float* __restrict__ books, float* __restrict__ ws){
  int row = blockIdx.x;            // 5120
  int t = threadIdx.x;             // 64
  const float4* p = (const float4*)(books + (size_t)row * 256);
  float4 v = p[t];
  float s = v.x*v.x + v.y*v.y + v.z*v.z + v.w*v.w;
  #pragma unroll
  for (int m = 1; m < 64; m <<= 1) s += __shfl_xor(s, m);
  if (t == 0) ws[F_BK2 + row] = s;
}

// ---------------------------------------------------------------------------
// K_cvt: books f32 -> bf16 row-major copy + bf16 transposed copy (per c)
// grid 80 = c(10) x k0(8 tiles of 64), 256 threads
// ---------------------------------------------------------------------------
__global__ void __launch_bounds__(256)
k_cvt(const float* __restrict__ books, uint16_t* __restrict__ bkrm,
      uint16_t* __restrict__ bkTg){
  __shared__ __align__(16) char tsm[32768];   // [64][256] bf16, swizzled
  int c = blockIdx.x >> 3, k0 = (blockIdx.x & 7) << 6;
  int t = threadIdx.x;
  #pragma unroll
  for (int q = 0; q < 16; ++q){
    int e = q * 1024 + t * 4;
    int kk = e >> 8, d = e & 255;
    float4 v = *(const float4*)(books + ((size_t)(c*512 + k0 + kk))*256 + d);
    uint32_t lo = pk2(v.x, v.y), hi = pk2(v.z, v.w);
    uint2 h; h.x = lo; h.y = hi;
    *(uint2*)(bkrm + ((size_t)(c*512 + k0 + kk))*256 + d) = h;
    int base = (kk << 9) + (d << 1);
    *(uint2*)(tsm + (base ^ ((kk & 7) << 4))) = h;
  }
  __syncthreads();
  int d = t;
  uint16_t tmp[64];
  #pragma unroll
  for (int kk = 0; kk < 64; ++kk)
    tmp[kk] = *(uint16_t*)(tsm + (((kk << 9) + (d << 1)) ^ ((kk & 7) << 4)));
  #pragma unroll
  for (int q = 0; q < 8; ++q)
    *(uint4*)(bkTg + ((size_t)(c*256 + d))*512 + k0 + q*8) = *(uint4*)&tmp[q*8];
}

// ---------------------------------------------------------------------------
// K_zq_mfma: grid 640 = b(32) x c(10) x ntile(2 of 128 rows), 512 threads.
// Wave w owns rows n0+16w..+16. Flash over k in pairs of 32.
// ---------------------------------------------------------------------------
__global__ void __launch_bounds__(512)
k_zq_mfma(const float* __restrict__ ze, const uint16_t* __restrict__ bkrm,
          const uint16_t* __restrict__ bkTg, const float* __restrict__ ws,
          const float* __restrict__ lpq, uint16_t* __restrict__ part){
  __shared__ __align__(16) char sm[44032];
  // 0: bk [32][256] bf16 swz | 16384: bkT [128][64] bf16 swz | 32768: P per-wave [16][36] u16 | 41984: bk2 f32[512]
  const int B = blockIdx.x;
  const int b = B / 20, rem = B % 20, c = rem >> 1, nt = rem & 1;
  const int n0 = nt << 7;
  const int tid = threadIdx.x;
  const int w = tid >> 6, lane = tid & 63, g = lane >> 4, r16 = lane & 15;
  const float pq = 0.5f / fmaxf(1.0f + __expf(lpq[0]), 1e-10f);
  const float cpc = ws[b * 10 + c];
  uint32_t ke0, ke1; tf2x32(0u, 42u, 0u, 1u, ke0, ke1);  // ke = tf(key,(0,1))

  float* bk2s = (float*)(sm + 41984);
  bk2s[tid] = ws[F_BK2 + c * 512 + tid];

  // ze A-frags in registers: za[dt] holds ze[n0+16w+r16][dt*32 + 8g .. +8]
  bf16x8 za[8];
  {
    const float* zp = ze + ((size_t)(b * 256 + n0 + w * 16 + r16)) * 256 + g * 8;
    #pragma unroll
    for (int dt = 0; dt < 8; ++dt){
      float4 v0 = *(const float4*)(zp + dt * 32);
      float4 v1 = *(const float4*)(zp + dt * 32 + 4);
      bf16x8 z;
      z[0]=(__bf16)v0.x; z[1]=(__bf16)v0.y; z[2]=(__bf16)v0.z; z[3]=(__bf16)v0.w;
      z[4]=(__bf16)v1.x; z[5]=(__bf16)v1.y; z[6]=(__bf16)v1.z; z[7]=(__bf16)v1.w;
      za[dt] = z;
    }
  }

  f32x4 o[16];
  #pragma unroll
  for (int i = 0; i < 16; ++i) o[i] = (f32x4)(0.f);
  float m[4] = {-1e30f,-1e30f,-1e30f,-1e30f};
  float l[4] = {0.f,0.f,0.f,0.f};
  const uint32_t nb_row = ((uint32_t)((b*10 + c)*256 + n0 + w*16 + g*4)) << 9;
  char* pl = sm + 32768 + w * 1152;

  for (int p = 0; p < 16; ++p){
    const int kb = p << 5;
    __syncthreads();
    { // stage bk [32][256]
      int k = tid >> 4, d16 = (tid & 15) << 4;
      const uint4* src = (const uint4*)(bkrm + ((size_t)(c*512 + kb + k))*256 + d16);
      uint4 A = src[0], Bv = src[1];
      int base = (k << 9) + (d16 << 1), sw = (k & 7) << 4;
      *(uint4*)(sm + ( base       ^ sw)) = A;
      *(uint4*)(sm + ((base + 16) ^ sw)) = Bv;
    }
    { // stage bkT [128][64] (row d>>1, col-half d&1)
      int d = tid >> 1, kh = (tid & 1) << 4;
      const uint4* src = (const uint4*)(bkTg + ((size_t)(c*256 + d))*512 + kb + kh);
      uint4 A = src[0], Bv = src[1];
      int base = 16384 + ((d >> 1) << 7) + ((((d & 1) << 5) + kh) << 1);
      int sw = ((d >> 1) & 7) << 4;
      *(uint4*)(sm + ( base       ^ sw)) = A;
      *(uint4*)(sm + ((base + 16) ^ sw)) = Bv;
    }
    __syncthreads();

    // QK: S rows = n_pt (4g+i), cols = k (r16, two 16-tiles)
    f32x4 acc0 = (f32x4)(0.f), acc1 = (f32x4)(0.f);
    #pragma unroll
    for (int dt = 0; dt < 8; ++dt){
      int d0b = ((dt * 32 + g * 8) << 1);
      int row0 = r16, row1 = 16 + r16;
      bf16x8 f0 = *(bf16x8*)(sm + (((row0 << 9) + d0b) ^ ((row0 & 7) << 4)));
      bf16x8 f1 = *(bf16x8*)(sm + (((row1 << 9) + d0b) ^ ((row1 & 7) << 4)));
      acc0 = __builtin_amdgcn_mfma_f32_16x16x32_bf16(za[dt], f0, acc0, 0, 0, 0);
      acc1 = __builtin_amdgcn_mfma_f32_16x16x32_bf16(za[dt], f1, acc1, 0, 0, 0);
    }

    // logits + gumbel
    float bv0 = bk2s[kb + r16], bv1 = bk2s[kb + 16 + r16];
    float v0[4], v1[4];
    #pragma unroll
    for (int i = 0; i < 4; ++i){
      uint32_t idx0 = nb_row + (uint32_t)(i * 512) + (uint32_t)(kb + r16);
      v0[i] = (-pq * (bv0 - 2.f * acc0[i]) + gum_at(ke0, ke1, idx0)) * 2.f;
      v1[i] = (-pq * (bv1 - 2.f * acc1[i]) + gum_at(ke0, ke1, idx0 + 16u)) * 2.f;
    }
    // per-row pair max (reduce over 16-lane group)
    float mr[4];
    #pragma unroll
    for (int i = 0; i < 4; ++i){
      float x = fmaxf(v0[i], v1[i]);
      x = fmaxf(x, __shfl_xor(x, 1)); x = fmaxf(x, __shfl_xor(x, 2));
      x = fmaxf(x, __shfl_xor(x, 4)); x = fmaxf(x, __shfl_xor(x, 8));
      mr[i] = x;
    }
    bool need = (mr[0] > m[0] + 8.f) | (mr[1] > m[1] + 8.f) |
                (mr[2] > m[2] + 8.f) | (mr[3] > m[3] + 8.f);
    if (__any(need)){
      float sc[4];
      #pragma unroll
      for (int i = 0; i < 4; ++i){
        float mn = fmaxf(m[i], mr[i]);
        sc[i] = __expf(m[i] - mn);
        m[i] = mn; l[i] *= sc[i];
      }
      #pragma unroll
      for (int dt = 0; dt < 16; ++dt){
        o[dt][0] *= sc[0]; o[dt][1] *= sc[1]; o[dt][2] *= sc[2]; o[dt][3] *= sc[3];
      }
    }
    // P + per-lane partial l + stage P to LDS (wave-private)
    #pragma unroll
    for (int i = 0; i < 4; ++i){
      float p0 = __expf(v0[i] - m[i]);
      float p1 = __expf(v1[i] - m[i]);
      l[i] += p0 + p1;
      *(uint16_t*)(pl + (4*g + i)*72 + (r16 << 1))        = bfbits(p0);
      *(uint16_t*)(pl + (4*g + i)*72 + ((16 + r16) << 1)) = bfbits(p1);
    }
    asm volatile("s_waitcnt lgkmcnt(0)" ::: "memory");
    // PV: A = P (rows r16, k = 8g+j), B = bkT (k rows, d cols)
    union U8 { bf16x8 f; uint32_t u[4]; };
    U8 pa;
    {
      char* pb = pl + r16 * 72 + (g << 4);
      *(uint2*)&pa.u[0] = *(uint2*)pb;
      *(uint2*)&pa.u[2] = *(uint2*)(pb + 8);
    }
    #pragma unroll
    for (int dt = 0; dt < 16; ++dt){
      int d = (dt << 4) + r16;
      int base = 16384 + ((d >> 1) << 7) + ((((d & 1) << 5) + (g << 3)) << 1);
      int sw = ((d >> 1) & 7) << 4;
      U8 bf;
      *(uint2*)&bf.u[0] = *(uint2*)(sm + ( base      ^ sw));
      *(uint2*)&bf.u[2] = *(uint2*)(sm + ((base + 8) ^ sw));
      o[dt] = __builtin_amdgcn_mfma_f32_16x16x32_bf16(pa.f, bf.f, o[dt], 0, 0, 0);
    }
  }

  float lf[4];
  #pragma unroll
  for (int i = 0; i < 4; ++i){
    float x = l[i];
    x += __shfl_xor(x, 1); x += __shfl_xor(x, 2);
    x += __shfl_xor(x, 4); x += __shfl_xor(x, 8);
    lf[i] = cpc / x;
  }
  uint16_t* dst = part + ((size_t)((b*10 + c)*256 + n0 + w*16 + g*4))*256 + r16;
  #pragma unroll
  for (int i = 0; i < 4; ++i){
    #pragma unroll
    for (int dt = 0; dt < 16; ++dt){
      dst[(size_t)i * 256 + dt * 16] = bfbits(o[dt][i] * lf[i]);
    }
  }
}

// ---------------------------------------------------------------------------
// K_comb: zq = sum_c partials (bf16 -> f32). grid 1024 x 256.
// ---------------------------------------------------------------------------
__global__ void __launch_bounds__(256)
k_comb(const uint16_t* __restrict__ part, float* __restrict__ zq){
  int t = blockIdx.x * 256 + threadIdx.x;       // 262144 units of 8 elems
  int b = t >> 13, n = (t >> 5) & 255, dc = (t & 31) << 3;
  float acc[8];
  #pragma unroll
  for (int j = 0; j < 8; ++j) acc[j] = 0.f;
  #pragma unroll
  for (int c = 0; c < 10; ++c){
    const uint16_t* p = part + ((size_t)((b*10 + c)*256 + n))*256 + dc;
    uint4 v = *(const uint4*)p;
    uint32_t uu[4] = {v.x, v.y, v.z, v.w};
    #pragma unroll
    for (int q = 0; q < 4; ++q){
      acc[2*q]   += __uint_as_float((uu[q] & 0xFFFFu) << 16);
      acc[2*q+1] += __uint_as_float((uu[q] >> 16) << 16);
    }
  }
  float* dstp = zq + ((size_t)(b*256 + n))*256 + dc;
  float4 r0 = {acc[0], acc[1], acc[2], acc[3]};
  float4 r1 = {acc[4], acc[5], acc[6], acc[7]};
  *(float4*)dstp = r0;
  *(float4*)(dstp + 4) = r1;
}

// ---------------------------------------------------------------------------
// K3: mixed codebook M[b][k][d] (for prob path)
// ---------------------------------------------------------------------------
__global__ void k_mix(const float* __restrict__ books, const float* __restrict__ ws,
                      float* __restrict__ M){
  int b = blockIdx.x >> 9, k = blockIdx.x & 511, t = threadIdx.x;
  float4 acc = make_float4(0.f, 0.f, 0.f, 0.f);
  #pragma unroll
  for (int c = 0; c < 10; ++c){
    float wv = ws[384 + b * 10 + c];
    float4 v = ((const float4*)books)[((size_t)(c * 512 + k)) * 64 + t];
    acc.x = fmaf(wv, v.x, acc.x); acc.y = fmaf(wv, v.y, acc.y);
    acc.z = fmaf(wv, v.z, acc.z); acc.w = fmaf(wv, v.w, acc.w);
  }
  ((float4*)M)[((size_t)(b * 512 + k)) * 64 + t] = acc;
}

// ---------------------------------------------------------------------------
// K4: prob / log_prob (unchanged from R2)
// ---------------------------------------------------------------------------
template<int USE_M>
__global__ void __launch_bounds__(256)
k_probs(const float* __restrict__ ze, const float* __restrict__ books,
        const float* __restrict__ M, const float* __restrict__ ws,
        const float* __restrict__ lpq,
        float* __restrict__ prob, float* __restrict__ logp){
  __shared__ float ze_t[16][256];
  __shared__ float m_t[32][256];
  __shared__ float s_l[16][512];
  int B = blockIdx.x, b = B >> 4, n0 = (B & 15) << 4;
  int t = threadIdx.x, r = t >> 4, u = t & 15;
  float pq = 0.5f / fmaxf(1.0f + __expf(lpq[0]), 1e-10f);
  float cp[10];
  #pragma unroll
  for (int c = 0; c < 10; ++c) cp[c] = ws[384 + b * 10 + c];
  const float4* zsrc = (const float4*)(ze + ((size_t)(b * 256 + n0)) * 256);
  for (int q = t; q < 1024; q += 256){
    int rr = q >> 6, d4 = q & 63;
    float4 v = zsrc[q];
    *(float4*)&ze_t[rr][((d4 ^ (rr & 7)) << 2)] = v;
  }
  for (int ci = 0; ci < 16; ++ci){
    __syncthreads();
    int k0 = ci << 5;
    for (int q = t; q < 2048; q += 256){
      int kk = q >> 6, d4 = q & 63;
      float4 v;
      if (USE_M){
        v = ((const float4*)M)[((size_t)(b * 512 + k0 + kk)) * 64 + d4];
      } else {
        v = make_float4(0.f, 0.f, 0.f, 0.f);
        #pragma unroll
        for (int c = 0; c < 10; ++c){
          float4 wv = ((const float4*)books)[((size_t)(c * 512 + k0 + kk)) * 64 + d4];
          v.x = fmaf(cp[c], wv.x, v.x); v.y = fmaf(cp[c], wv.y, v.y);
          v.z = fmaf(cp[c], wv.z, v.z); v.w = fmaf(cp[c], wv.w, v.w);
        }
      }
      *(float4*)&m_t[kk][((d4 ^ (kk & 7)) << 2)] = v;
    }
    __syncthreads();
    float s0 = 0.f, s1 = 0.f;
    #pragma unroll 8
    for (int d4 = 0; d4 < 64; ++d4){
      float4 z  = *(const float4*)&ze_t[r][((d4 ^ (r & 7)) << 2)];
      float4 a  = *(const float4*)&m_t[u][((d4 ^ (u & 7)) << 2)];
      float4 bb = *(const float4*)&m_t[u + 16][((d4 ^ (u & 7)) << 2)];
      s0 = fmaf(z.x,a.x,s0);  s0 = fmaf(z.y,a.y,s0);  s0 = fmaf(z.z,a.z,s0);  s0 = fmaf(z.w,a.w,s0);
      s1 = fmaf(z.x,bb.x,s1); s1 = fmaf(z.y,bb.y,s1); s1 = fmaf(z.z,bb.z,s1); s1 = fmaf(z.w,bb.w,s1);
    }
    s_l[r][k0 + u]      = s0;
    s_l[r][k0 + 16 + u] = s1;
  }
  float mx = -1e30f;
  for (int j = 0; j < 32; ++j){
    int k = (j << 4) + u;
    float beta = 0.f;
    #pragma unroll
    for (int c = 0; c < 10; ++c) beta = fmaf(cp[c], ws[F_BK2 + (c << 9) + k], beta);
    float v = -pq * (beta - 2.0f * s_l[r][k]);
    s_l[r][k] = v;
    mx = fmaxf(mx, v);
  }
  #pragma unroll
  for (int mm = 1; mm < 16; mm <<= 1) mx = fmaxf(mx, __shfl_xor(mx, mm));
  float s = 0.f;
  for (int j = 0; j < 32; ++j) s += __expf(s_l[r][(j << 4) + u] - mx);
  #pragma unroll
  for (int mm = 1; mm < 16; mm <<= 1) s += __shfl_xor(s, mm);
  float lse = mx + __logf(s);
  size_t base = ((size_t)(b * 256 + n0 + r)) * 512;
  for (int j = 0; j < 32; ++j){
    int k = (j << 4) + u;
    float lp = s_l[r][k] - lse;
    prob[base + k] = __expf(lp);
    logp[base + k] = lp;
  }
}

// ---------------------------------------------------------------------------
// Fallback (R2) k_zq — used only if ws too small for the mfma path.
// ---------------------------------------------------------------------------
__global__ void __launch_bounds__(256)
k_zq_old(const float* __restrict__ ze, const float* __restrict__ books,
         const float* __restrict__ ws, const float* __restrict__ lpq,
         float* __restrict__ zq){
  __shared__ float ze_t[32][256];
  __shared__ float b_t[32][256];
  int B = blockIdx.x, b = B >> 3, n0 = (B & 7) << 5;
  int t = threadIdx.x, r = t >> 3, u = t & 7, lane = t & 63;
  float pq = 0.5f / fmaxf(1.0f + __expf(lpq[0]), 1e-10f);
  uint32_t ke0, ke1; tf2x32(0u, 42u, 0u, 1u, ke0, ke1);
  const float4* zsrc = (const float4*)(ze + ((size_t)(b * 256 + n0)) * 256);
  for (int q = t; q < 2048; q += 256){
    int rr = q >> 6, d4 = q & 63;
    float4 v = zsrc[q];
    *(float4*)&ze_t[rr][((d4 ^ (rr & 7)) << 2)] = v;
  }
  float4 zqa[8];
  #pragma unroll
  for (int mm = 0; mm < 8; ++mm) zqa[mm] = make_float4(0.f, 0.f, 0.f, 0.f);
  int nglob = n0 + r;
  for (int c = 0; c < 10; ++c){
    float cpc = ws[b * 10 + c];
    uint32_t nbase = ((uint32_t)((b * 10 + c) * 256 + nglob)) << 9;
    float m = -1e30f, l = 0.f;
    float4 pz[8];
    #pragma unroll
    for (int mm = 0; mm < 8; ++mm) pz[mm] = make_float4(0.f, 0.f, 0.f, 0.f);
    for (int ci = 0; ci < 16; ++ci){
      __syncthreads();
      const float4* bsrc = (const float4*)(books + ((size_t)(c * 512 + (ci << 5))) * 256);
      for (int q = t; q < 2048; q += 256){
        int kk = q >> 6, d4 = q & 63;
        float4 v = bsrc[q];
        *(float4*)&b_t[kk][((d4 ^ (kk & 7)) << 2)] = v;
      }
      __syncthreads();
      float s0 = 0.f, s1 = 0.f, s2 = 0.f, s3 = 0.f;
      #pragma unroll 8
      for (int d4 = 0; d4 < 64; ++d4){
        float4 z  = *(const float4*)&ze_t[r][((d4 ^ (r & 7)) << 2)];
        float4 b0 = *(const float4*)&b_t[u][((d4 ^ (u & 7)) << 2)];
        float4 b1 = *(const float4*)&b_t[u + 8][((d4 ^ (u & 7)) << 2)];
        float4 b2 = *(const float4*)&b_t[u + 16][((d4 ^ (u & 7)) << 2)];
        float4 b3 = *(const float4*)&b_t[u + 24][((d4 ^ (u & 7)) << 2)];
        s0 = fmaf(z.x,b0.x,s0); s0 = fmaf(z.y,b0.y,s0); s0 = fmaf(z.z,b0.z,s0); s0 = fmaf(z.w,b0.w,s0);
        s1 = fmaf(z.x,b1.x,s1); s1 = fmaf(z.y,b1.y,s1); s1 = fmaf(z.z,b1.z,s1); s1 = fmaf(z.w,b1.w,s1);
        s2 = fmaf(z.x,b2.x,s2); s2 = fmaf(z.y,b2.y,s2); s2 = fmaf(z.z,b2.z,s2); s2 = fmaf(z.w,b2.w,s2);
        s3 = fmaf(z.x,b3.x,s3); s3 = fmaf(z.y,b3.y,s3); s3 = fmaf(z.z,b3.z,s3); s3 = fmaf(z.w,b3.w,s3);
      }
      float ss[4] = {s0, s1, s2, s3};
      float vv[4]; float cm = -1e30f;
      #pragma unroll
      for (int jj = 0; jj < 4; ++jj){
        int kg = (ci << 5) + (jj << 3) + u;
        float bk2v = ws[F_BK2 + (c << 9) + kg];
        float gg = gum_at(ke0, ke1, nbase + (uint32_t)kg);
        float v = (-pq * (bk2v - 2.0f * ss[jj]) + gg) * 2.0f;
        vv[jj] = v; cm = fmaxf(cm, v);
      }
      cm = fmaxf(cm, __shfl_xor(cm, 1));
      cm = fmaxf(cm, __shfl_xor(cm, 2));
      cm = fmaxf(cm, __shfl_xor(cm, 4));
      float mn = fmaxf(m, cm);
      float scale = __expf(m - mn);
      float csum = 0.f;
      #pragma unroll
      for (int jj = 0; jj < 4; ++jj){ vv[jj] = __expf(vv[jj] - mn); csum += vv[jj]; }
      csum += __shfl_xor(csum, 1);
      csum += __shfl_xor(csum, 2);
      csum += __shfl_xor(csum, 4);
      l = l * scale + csum;
      m = mn;
      #pragma unroll
      for (int mm = 0; mm < 8; ++mm){
        pz[mm].x *= scale; pz[mm].y *= scale; pz[mm].z *= scale; pz[mm].w *= scale;
      }
      #pragma unroll
      for (int jj = 0; jj < 4; ++jj){
        float pv = vv[jj];
        #pragma unroll
        for (int q2 = 0; q2 < 8; ++q2){
          float wk = __shfl(pv, (lane & 56) | q2, 64);
          int kl = (jj << 3) + q2;
          #pragma unroll
          for (int mm = 0; mm < 8; ++mm){
            float4 bv = *(const float4*)&b_t[kl][(((u + (mm << 3)) ^ (kl & 7)) << 2)];
            pz[mm].x = fmaf(wk, bv.x, pz[mm].x);
            pz[mm].y = fmaf(wk, bv.y, pz[mm].y);
            pz[mm].z = fmaf(wk, bv.z, pz[mm].z);
            pz[mm].w = fmaf(wk, bv.w, pz[mm].w);
          }
        }
      }
    }
    float wc = cpc / l;
    #pragma unroll
    for (int mm = 0; mm < 8; ++mm){
      zqa[mm].x = fmaf(wc, pz[mm].x, zqa[mm].x);
      zqa[mm].y = fmaf(wc, pz[mm].y, zqa[mm].y);
      zqa[mm].z = fmaf(wc, pz[mm].z, zqa[mm].z);
      zqa[mm].w = fmaf(wc, pz[mm].w, zqa[mm].w);
    }
  }
  float* dst = zq + ((size_t)(b * 256 + nglob)) * 256;
  #pragma unroll
  for (int mm = 0; mm < 8; ++mm)
    *(float4*)&dst[(u << 2) + (mm << 5)] = zqa[mm];
}

// ---------------------------------------------------------------------------
extern "C" void kernel_launch(void* const* d_in, const int* in_sizes, int n_in,
                              void* d_out, int out_size, void* d_ws, size_t ws_size,
                              hipStream_t stream){
  (void)in_sizes; (void)n_in; (void)out_size;
  const float* ze    = (const float*)d_in[0];
  const float* cl    = (const float*)d_in[1];
  const float* books = (const float*)d_in[2];
  const float* lpq   = (const float*)d_in[3];
  const float* lpqc  = (const float*)d_in[4];
  float* out  = (float*)d_out;
  float* ws   = (float*)d_ws;
  float* zq   = out;
  float* prob = out + 2097153;
  float* logp = out + 2097153 + 4194304;
  size_t wsf = ws_size / 4;

  k_cprob<<<1, 64, 0, stream>>>(cl, lpq, lpqc, ws, out);
  k_bk2<<<5120, 64, 0, stream>>>(books, ws);

  bool tierB = wsf >= (size_t)F_M;            // mfma path + partials fit
  bool tierA = wsf >= (size_t)F_ENDA;         // + mixed codebook M
  if (tierB){
    uint16_t* bkrm = (uint16_t*)(ws + F_BKRM);
    uint16_t* bkTg = (uint16_t*)(ws + F_BKT);
    uint16_t* part = (uint16_t*)(ws + F_PART);
    k_cvt<<<80, 256, 0, stream>>>(books, bkrm, bkTg);
    if (tierA){
      float* M = ws + F_M;
      k_mix<<<16384, 64, 0, stream>>>(books, ws, M);
      k_probs<1><<<512, 256, 0, stream>>>(ze, books, M, ws, lpq, prob, logp);
    } else {
      k_probs<0><<<512, 256, 0, stream>>>(ze, books, nullptr, ws, lpq, prob, logp);
    }
    k_zq_mfma<<<640, 512, 0, stream>>>(ze, bkrm, bkTg, ws, lpq, part);
    k_comb<<<1024, 256, 0, stream>>>(part, zq);
  } else {
    bool useM = wsf >= (size_t)(8192 + 4194304);
    if (useM){
      float* M = ws + 8192;
      k_mix<<<16384, 64, 0, stream>>>(books, ws, M);
      k_probs<1><<<512, 256, 0, stream>>>(ze, books, M, ws, lpq, prob, logp);
    } else {
      k_probs<0><<<512, 256, 0, stream>>>(ze, books, nullptr, ws, lpq, prob, logp);
    }
    k_zq_old<<<256, 256, 0, stream>>>(ze, books, ws, lpq, zq);
  }
}

// Round 4
// 454.372 us; speedup vs baseline: 4.8801x; 1.0538x over previous
//
#include <hip/hip_runtime.h>
#include <stdint.h>

// ---------------------------------------------------------------------------
// GaussianVectorQuantizer (training) MI355X.
// Outputs (flat f32): zq[2097152] | precision_q[1] | prob[4194304] | log_prob[4194304]
// RNG (verified R2): threefry2x32 partitionable, fold-like split, draw = o0^o1.
// R4: k_zq split over k-halves (grid 1280) + reg-prefetch pipeline + setprio;
//     LSE-based half-combine; merged prep kernel; bf16 mixed codebook M.
// ---------------------------------------------------------------------------

typedef __attribute__((ext_vector_type(8))) __bf16 bf16x8;
typedef __attribute__((ext_vector_type(4))) float f32x4;

// ws float-offsets
#define F_CP     0
#define F_BK2    1024
#define O_BKRM   8192u
#define O_BKT    663552u      // 8192 + 10*512*256/2
#define O_M      1318912u     // + 655360
#define O_LSE    3416064u     // + 32*512*256/2
#define O_PART   3579904u     // + 163840

__device__ __forceinline__ uint32_t rotl32(uint32_t x, int r){ return (x << r) | (x >> (32 - r)); }

__device__ __forceinline__ void tf2x32(uint32_t k0, uint32_t k1, uint32_t x0, uint32_t x1,
                                       uint32_t &o0, uint32_t &o1){
  uint32_t k2 = k0 ^ k1 ^ 0x1BD11BDAu;
  x0 += k0; x1 += k1;
#define TFR(r) { x0 += x1; x1 = rotl32(x1,(r)); x1 ^= x0; }
  TFR(13) TFR(15) TFR(26) TFR(6)
  x0 += k1; x1 += k2 + 1u;
  TFR(17) TFR(29) TFR(16) TFR(24)
  x0 += k2; x1 += k0 + 2u;
  TFR(13) TFR(15) TFR(26) TFR(6)
  x0 += k0; x1 += k1 + 3u;
  TFR(17) TFR(29) TFR(16) TFR(24)
  x0 += k1; x1 += k2 + 4u;
  TFR(13) TFR(15) TFR(26) TFR(6)
  x0 += k2; x1 += k0 + 5u;
#undef TFR
  o0 = x0; o1 = x1;
}

__device__ __forceinline__ uint32_t rbits0(uint32_t k0, uint32_t k1, uint32_t i){
  uint32_t o0, o1; tf2x32(k0, k1, 0u, i, o0, o1); return o0 ^ o1;
}
__device__ __forceinline__ float bits_to_u01(uint32_t b){
  return __uint_as_float((b >> 9) | 0x3F800000u) - 1.0f;
}
__device__ __forceinline__ float gumbel_u(float u){
  return -__logf(-__logf(u + 1e-10f) + 1e-10f);
}
__device__ __forceinline__ float gum_at(uint32_t k0, uint32_t k1, uint32_t idx){
  return gumbel_u(bits_to_u01(rbits0(k0, k1, idx)));
}
__device__ __forceinline__ uint16_t bfbits(float x){
  union { __bf16 h; uint16_t s; } u; u.h = (__bf16)x; return u.s;
}
__device__ __forceinline__ uint32_t pk2(float a, float b){
  return (uint32_t)bfbits(a) | ((uint32_t)bfbits(b) << 16);
}
__device__ __forceinline__ float bflo(uint32_t u){ return __uint_as_float((u & 0xFFFFu) << 16); }
__device__ __forceinline__ float bfhi(uint32_t u){ return __uint_as_float((u >> 16) << 16); }

// ---------------------------------------------------------------------------
// k_prep: books f32 -> bkrm bf16 + bkT bf16; bk2 row sums (f32); cprob; precision_q.
// grid 80 = c(10) x k0(8 tiles of 64 rows), 256 threads.
// ---------------------------------------------------------------------------
__global__ void __launch_bounds__(256)
k_prep(const float* __restrict__ books, const float* __restrict__ c_logits,
       const float* __restrict__ lpq, const float* __restrict__ lpqc,
       float* __restrict__ ws, float* __restrict__ out,
       uint16_t* __restrict__ bkrm, uint16_t* __restrict__ bkTg){
  __shared__ __align__(16) char tsm[32768];   // [64][256] bf16, swizzled
  int c = blockIdx.x >> 3, k0 = (blockIdx.x & 7) << 6;
  int t = threadIdx.x, lane = t & 63, w4 = t >> 6;
  #pragma unroll
  for (int q = 0; q < 16; ++q){
    int kk = q * 4 + w4, d = lane * 4;
    float4 v = *(const float4*)(books + ((size_t)(c*512 + k0 + kk))*256 + d);
    // bk2: wave covers the full row
    float s = v.x*v.x + v.y*v.y + v.z*v.z + v.w*v.w;
    #pragma unroll
    for (int m = 1; m < 64; m <<= 1) s += __shfl_xor(s, m);
    if (lane == 0) ws[F_BK2 + c*512 + k0 + kk] = s;
    uint2 h; h.x = pk2(v.x, v.y); h.y = pk2(v.z, v.w);
    *(uint2*)(bkrm + ((size_t)(c*512 + k0 + kk))*256 + d) = h;
    int base = (kk << 9) + (d << 1);
    *(uint2*)(tsm + (base ^ ((kk & 7) << 4))) = h;
  }
  __syncthreads();
  {
    int d = t;
    uint16_t tmp[64];
    #pragma unroll
    for (int kk = 0; kk < 64; ++kk)
      tmp[kk] = *(uint16_t*)(tsm + (((kk << 9) + (d << 1)) ^ ((kk & 7) << 4)));
    #pragma unroll
    for (int q = 0; q < 8; ++q)
      *(uint4*)(bkTg + ((size_t)(c*256 + d))*512 + k0 + q*8) = *(uint4*)&tmp[q*8];
  }
  if (blockIdx.x == 0){
    if (t == 0) out[2097152] = 0.5f / fmaxf(1.0f + __expf(lpq[0]), 1e-10f);
    if (t < 32){
      int b = t;
      float pqc = 0.5f / fmaxf(1.0f + __expf(lpqc[0]), 1e-10f);
      uint32_t kc0, kc1; tf2x32(0u, 42u, 0u, 0u, kc0, kc1);
      float y[10]; float mx = -1e30f;
      #pragma unroll
      for (int c2 = 0; c2 < 10; ++c2){
        float g = gum_at(kc0, kc1, (uint32_t)(b * 10 + c2));
        float v = (c_logits[b * 10 + c2] * pqc + g) * 2.0f;
        y[c2] = v; mx = fmaxf(mx, v);
      }
      float s = 0.f;
      #pragma unroll
      for (int c2 = 0; c2 < 10; ++c2){ y[c2] = __expf(y[c2] - mx); s += y[c2]; }
      float inv = 1.0f / s;
      #pragma unroll
      for (int c2 = 0; c2 < 10; ++c2) ws[F_CP + b * 10 + c2] = y[c2] * inv;
    }
  }
}

// ---------------------------------------------------------------------------
// k_mix: M_b[k][d] = sum_c cp[b,c]*books[c,k,d]  (bf16 in, bf16 out)
// grid 4096 = b(32) x kgroup(128 of 4 rows), 256 threads (4 waves, 1 row each)
// ---------------------------------------------------------------------------
__global__ void __launch_bounds__(256)
k_mix(const uint16_t* __restrict__ bkrm, const float* __restrict__ ws,
      uint16_t* __restrict__ Mh){
  int blk = blockIdx.x;
  int b = blk >> 7, kg = blk & 127;
  int t = threadIdx.x, kr = t >> 6, lane = t & 63;
  int k = kg * 4 + kr, d = lane * 4;
  float a0=0.f, a1=0.f, a2=0.f, a3=0.f;
  #pragma unroll
  for (int c = 0; c < 10; ++c){
    float cp = ws[F_CP + b*10 + c];
    uint2 v = *(const uint2*)(bkrm + ((size_t)(c*512 + k))*256 + d);
    a0 = fmaf(cp, bflo(v.x), a0); a1 = fmaf(cp, bfhi(v.x), a1);
    a2 = fmaf(cp, bflo(v.y), a2); a3 = fmaf(cp, bfhi(v.y), a3);
  }
  uint2 h; h.x = pk2(a0, a1); h.y = pk2(a2, a3);
  *(uint2*)(Mh + ((size_t)(b*512 + k))*256 + d) = h;
}

// ---------------------------------------------------------------------------
// k_probs: prob / log_prob.  16 rows/block, 256 threads.
// USE_M=1: stage bf16 M -> f32 LDS.  USE_M=0: mix books f32 on the fly.
// ---------------------------------------------------------------------------
template<int USE_M>
__global__ void __launch_bounds__(256)
k_probs(const float* __restrict__ ze, const float* __restrict__ books,
        const uint16_t* __restrict__ Mh, const float* __restrict__ ws,
        const float* __restrict__ lpq,
        float* __restrict__ prob, float* __restrict__ logp){
  __shared__ float ze_t[16][256];
  __shared__ float m_t[32][256];
  __shared__ float s_l[16][512];
  int B = blockIdx.x, b = B >> 4, n0 = (B & 15) << 4;
  int t = threadIdx.x, r = t >> 4, u = t & 15;
  float pq = 0.5f / fmaxf(1.0f + __expf(lpq[0]), 1e-10f);
  float cp[10];
  #pragma unroll
  for (int c = 0; c < 10; ++c) cp[c] = ws[F_CP + b * 10 + c];
  const float4* zsrc = (const float4*)(ze + ((size_t)(b * 256 + n0)) * 256);
  for (int q = t; q < 1024; q += 256){
    int rr = q >> 6, d4 = q & 63;
    float4 v = zsrc[q];
    *(float4*)&ze_t[rr][((d4 ^ (rr & 7)) << 2)] = v;
  }
  for (int ci = 0; ci < 16; ++ci){
    __syncthreads();
    int k0 = ci << 5;
    for (int q = t; q < 2048; q += 256){
      int kk = q >> 6, d4 = q & 63;
      float4 v;
      if (USE_M){
        uint2 mv = *(const uint2*)(Mh + ((size_t)(b*512 + k0 + kk))*256 + (d4 << 2));
        v.x = bflo(mv.x); v.y = bfhi(mv.x); v.z = bflo(mv.y); v.w = bfhi(mv.y);
      } else {
        v = make_float4(0.f, 0.f, 0.f, 0.f);
        #pragma unroll
        for (int c = 0; c < 10; ++c){
          float4 wv = ((const float4*)books)[((size_t)(c * 512 + k0 + kk)) * 64 + d4];
          v.x = fmaf(cp[c], wv.x, v.x); v.y = fmaf(cp[c], wv.y, v.y);
          v.z = fmaf(cp[c], wv.z, v.z); v.w = fmaf(cp[c], wv.w, v.w);
        }
      }
      *(float4*)&m_t[kk][((d4 ^ (kk & 7)) << 2)] = v;
    }
    __syncthreads();
    float s0 = 0.f, s1 = 0.f;
    #pragma unroll 8
    for (int d4 = 0; d4 < 64; ++d4){
      float4 z  = *(const float4*)&ze_t[r][((d4 ^ (r & 7)) << 2)];
      float4 a  = *(const float4*)&m_t[u][((d4 ^ (u & 7)) << 2)];
      float4 bb = *(const float4*)&m_t[u + 16][((d4 ^ (u & 7)) << 2)];
      s0 = fmaf(z.x,a.x,s0);  s0 = fmaf(z.y,a.y,s0);  s0 = fmaf(z.z,a.z,s0);  s0 = fmaf(z.w,a.w,s0);
      s1 = fmaf(z.x,bb.x,s1); s1 = fmaf(z.y,bb.y,s1); s1 = fmaf(z.z,bb.z,s1); s1 = fmaf(z.w,bb.w,s1);
    }
    s_l[r][k0 + u]      = s0;
    s_l[r][k0 + 16 + u] = s1;
  }
  float mx = -1e30f;
  for (int j = 0; j < 32; ++j){
    int k = (j << 4) + u;
    float beta = 0.f;
    #pragma unroll
    for (int c = 0; c < 10; ++c) beta = fmaf(cp[c], ws[F_BK2 + (c << 9) + k], beta);
    float v = -pq * (beta - 2.0f * s_l[r][k]);
    s_l[r][k] = v;
    mx = fmaxf(mx, v);
  }
  #pragma unroll
  for (int mm = 1; mm < 16; mm <<= 1) mx = fmaxf(mx, __shfl_xor(mx, mm));
  float s = 0.f;
  for (int j = 0; j < 32; ++j) s += __expf(s_l[r][(j << 4) + u] - mx);
  #pragma unroll
  for (int mm = 1; mm < 16; mm <<= 1) s += __shfl_xor(s, mm);
  float lse = mx + __logf(s);
  size_t base = ((size_t)(b * 256 + n0 + r)) * 512;
  for (int j = 0; j < 32; ++j){
    int k = (j << 4) + u;
    float lp = s_l[r][k] - lse;
    prob[base + k] = __expf(lp);
    logp[base + k] = lp;
  }
}

// ---------------------------------------------------------------------------
// k_zq_mfma<NP,NH>: grid 32*10*2*NH, 512 threads (8 waves x 16 rows).
// Each block: b, c, ntile(128 rows), khalf h -> NP k-pairs of 32.
// Writes bf16 Ohat = O/l and f32 LSE per row; combined in k_comb.
// ---------------------------------------------------------------------------
template<int NP, int NH>
__global__ void __launch_bounds__(512)
k_zq_mfma(const float* __restrict__ ze, const uint16_t* __restrict__ bkrm,
          const uint16_t* __restrict__ bkTg, const float* __restrict__ ws,
          const float* __restrict__ lpq, uint16_t* __restrict__ part,
          float* __restrict__ lseg){
  __shared__ __align__(16) char sm[44032];
  // 0: bk [32][256] bf16 swz | 16384: bkT [128][64] bf16 swz | 32768: P 8x[16][36] u16 | 41984: bk2 f32[<=512]
  const int B = blockIdx.x;
  const int b = B / (20 * NH);
  int rem = B % (20 * NH);
  const int c = rem / (2 * NH);
  rem = rem % (2 * NH);
  const int nt = rem / NH, h = rem % NH;
  const int n0 = nt << 7;
  const int kbase = h * NP * 32;
  const int tid = threadIdx.x;
  const int w = tid >> 6, lane = tid & 63, g = lane >> 4, r16 = lane & 15;
  const float pq = 0.5f / fmaxf(1.0f + __expf(lpq[0]), 1e-10f);
  uint32_t ke0, ke1; tf2x32(0u, 42u, 0u, 1u, ke0, ke1);

  float* bk2s = (float*)(sm + 41984);
  if (tid < NP * 32) bk2s[tid] = ws[F_BK2 + c * 512 + kbase + tid];

  // ze A-frags in registers
  bf16x8 za[8];
  {
    const float* zp = ze + ((size_t)(b * 256 + n0 + w * 16 + r16)) * 256 + g * 8;
    #pragma unroll
    for (int dt = 0; dt < 8; ++dt){
      float4 v0 = *(const float4*)(zp + dt * 32);
      float4 v1 = *(const float4*)(zp + dt * 32 + 4);
      bf16x8 z;
      z[0]=(__bf16)v0.x; z[1]=(__bf16)v0.y; z[2]=(__bf16)v0.z; z[3]=(__bf16)v0.w;
      z[4]=(__bf16)v1.x; z[5]=(__bf16)v1.y; z[6]=(__bf16)v1.z; z[7]=(__bf16)v1.w;
      za[dt] = z;
    }
  }

  f32x4 o[16];
  #pragma unroll
  for (int i = 0; i < 16; ++i) o[i] = (f32x4)(0.f);
  float m[4] = {-1e30f,-1e30f,-1e30f,-1e30f};
  float l[4] = {0.f,0.f,0.f,0.f};
  const uint32_t nb_row = ((uint32_t)((b*10 + c)*256 + n0 + w*16 + g*4)) << 9;
  char* pl = sm + 32768 + w * 1152;

  // staging thread mapping (constant over pairs)
  const int sk = tid >> 4, sd16 = (tid & 15) << 4;                 // bk
  const int td = tid >> 1, tkh = (tid & 1) << 4;                   // bkT
  uint4 pf0, pf1, pf2, pf3;
  auto LOADP = [&](int p){
    int kabs = kbase + p * 32;
    const uint4* s1 = (const uint4*)(bkrm + ((size_t)(c*512 + kabs + sk))*256 + sd16);
    pf0 = s1[0]; pf1 = s1[1];
    const uint4* s2 = (const uint4*)(bkTg + ((size_t)(c*256 + td))*512 + kabs + tkh);
    pf2 = s2[0]; pf3 = s2[1];
  };
  LOADP(0);

  for (int p = 0; p < NP; ++p){
    const int kb = p << 5;
    __syncthreads();
    { // write staged regs to LDS
      int base = (sk << 9) + (sd16 << 1), sw = (sk & 7) << 4;
      *(uint4*)(sm + ( base       ^ sw)) = pf0;
      *(uint4*)(sm + ((base + 16) ^ sw)) = pf1;
      int base2 = 16384 + ((td >> 1) << 7) + ((((td & 1) << 5) + tkh) << 1);
      int sw2 = ((td >> 1) & 7) << 4;
      *(uint4*)(sm + ( base2       ^ sw2)) = pf2;
      *(uint4*)(sm + ((base2 + 16) ^ sw2)) = pf3;
    }
    __syncthreads();
    if (p + 1 < NP) LOADP(p + 1);

    // QK
    f32x4 acc0 = (f32x4)(0.f), acc1 = (f32x4)(0.f);
    __builtin_amdgcn_s_setprio(1);
    #pragma unroll
    for (int dt = 0; dt < 8; ++dt){
      int d0b = ((dt * 32 + g * 8) << 1);
      int row0 = r16, row1 = 16 + r16;
      bf16x8 f0 = *(bf16x8*)(sm + (((row0 << 9) + d0b) ^ ((row0 & 7) << 4)));
      bf16x8 f1 = *(bf16x8*)(sm + (((row1 << 9) + d0b) ^ ((row1 & 7) << 4)));
      acc0 = __builtin_amdgcn_mfma_f32_16x16x32_bf16(za[dt], f0, acc0, 0, 0, 0);
      acc1 = __builtin_amdgcn_mfma_f32_16x16x32_bf16(za[dt], f1, acc1, 0, 0, 0);
    }
    __builtin_amdgcn_s_setprio(0);

    // logits + gumbel
    float bv0 = bk2s[kb + r16], bv1 = bk2s[kb + 16 + r16];
    float v0[4], v1[4];
    #pragma unroll
    for (int i = 0; i < 4; ++i){
      uint32_t idx0 = nb_row + (uint32_t)(i * 512) + (uint32_t)(kbase + kb + r16);
      v0[i] = (-pq * (bv0 - 2.f * acc0[i]) + gum_at(ke0, ke1, idx0)) * 2.f;
      v1[i] = (-pq * (bv1 - 2.f * acc1[i]) + gum_at(ke0, ke1, idx0 + 16u)) * 2.f;
    }
    float mr[4];
    #pragma unroll
    for (int i = 0; i < 4; ++i){
      float x = fmaxf(v0[i], v1[i]);
      x = fmaxf(x, __shfl_xor(x, 1)); x = fmaxf(x, __shfl_xor(x, 2));
      x = fmaxf(x, __shfl_xor(x, 4)); x = fmaxf(x, __shfl_xor(x, 8));
      mr[i] = x;
    }
    bool need = (mr[0] > m[0] + 8.f) | (mr[1] > m[1] + 8.f) |
                (mr[2] > m[2] + 8.f) | (mr[3] > m[3] + 8.f);
    if (__any(need)){
      float sc[4];
      #pragma unroll
      for (int i = 0; i < 4; ++i){
        float mn = fmaxf(m[i], mr[i]);
        sc[i] = __expf(m[i] - mn);
        m[i] = mn; l[i] *= sc[i];
      }
      #pragma unroll
      for (int dt = 0; dt < 16; ++dt){
        o[dt][0] *= sc[0]; o[dt][1] *= sc[1]; o[dt][2] *= sc[2]; o[dt][3] *= sc[3];
      }
    }
    #pragma unroll
    for (int i = 0; i < 4; ++i){
      float p0 = __expf(v0[i] - m[i]);
      float p1 = __expf(v1[i] - m[i]);
      l[i] += p0 + p1;
      *(uint16_t*)(pl + (4*g + i)*72 + (r16 << 1))        = bfbits(p0);
      *(uint16_t*)(pl + (4*g + i)*72 + ((16 + r16) << 1)) = bfbits(p1);
    }
    asm volatile("s_waitcnt lgkmcnt(0)" ::: "memory");
    union U8 { bf16x8 f; uint32_t u[4]; };
    U8 pa;
    {
      char* pb = pl + r16 * 72 + (g << 4);
      *(uint2*)&pa.u[0] = *(uint2*)pb;
      *(uint2*)&pa.u[2] = *(uint2*)(pb + 8);
    }
    __builtin_amdgcn_s_setprio(1);
    #pragma unroll
    for (int dt = 0; dt < 16; ++dt){
      int d = (dt << 4) + r16;
      int base = 16384 + ((d >> 1) << 7) + ((((d & 1) << 5) + (g << 3)) << 1);
      int sw = ((d >> 1) & 7) << 4;
      U8 bf;
      *(uint2*)&bf.u[0] = *(uint2*)(sm + ( base      ^ sw));
      *(uint2*)&bf.u[2] = *(uint2*)(sm + ((base + 8) ^ sw));
      o[dt] = __builtin_amdgcn_mfma_f32_16x16x32_bf16(pa.f, bf.f, o[dt], 0, 0, 0);
    }
    __builtin_amdgcn_s_setprio(0);
  }

  const int nrow = n0 + w*16 + g*4;
  size_t rowbase = ((size_t)((b*10 + c)*NH + h)*256 + nrow);
  float lf[4];
  #pragma unroll
  for (int i = 0; i < 4; ++i){
    float x = l[i];
    x += __shfl_xor(x, 1); x += __shfl_xor(x, 2);
    x += __shfl_xor(x, 4); x += __shfl_xor(x, 8);
    lf[i] = 1.0f / x;
    if (r16 == 0) lseg[rowbase + i] = m[i] + __logf(x);
  }
  uint16_t* dst = part + rowbase * 256 + r16;
  #pragma unroll
  for (int i = 0; i < 4; ++i){
    #pragma unroll
    for (int dt = 0; dt < 16; ++dt){
      dst[(size_t)i * 256 + dt * 16] = bfbits(o[dt][i] * lf[i]);
    }
  }
}

// ---------------------------------------------------------------------------
// k_comb<NH>: zq[b,n,:] = sum_{c,h} coef * Ohat.  grid 1024 x 256 (8 rows/blk).
// coef[c,h] = cp[b,c] * softmax_h(LSE[b,c,h,n])
// ---------------------------------------------------------------------------
template<int NH>
__global__ void __launch_bounds__(256)
k_comb(const uint16_t* __restrict__ part, const float* __restrict__ lseg,
       const float* __restrict__ ws, float* __restrict__ zq){
  __shared__ float coef[8][10 * NH];
  int row0 = blockIdx.x * 8;
  int t = threadIdx.x;
  if (t < 80){
    int rr = t / 10, c = t % 10;
    int rw = row0 + rr, b = rw >> 8, n = rw & 255;
    float cp = ws[F_CP + b * 10 + c];
    if (NH == 1){
      coef[rr][c] = cp;
    } else {
      size_t base = ((size_t)((b*10 + c)*NH))*256 + n;
      float l0 = lseg[base], l1 = lseg[base + 256];
      float mx = fmaxf(l0, l1);
      float e0 = __expf(l0 - mx), e1 = __expf(l1 - mx);
      float inv = cp / (e0 + e1);
      coef[rr][c * NH]     = e0 * inv;
      coef[rr][c * NH + 1] = e1 * inv;
    }
  }
  __syncthreads();
  int rr = t >> 5, dc = (t & 31) << 3;
  int rw = row0 + rr, b = rw >> 8, n = rw & 255;
  float acc[8];
  #pragma unroll
  for (int j = 0; j < 8; ++j) acc[j] = 0.f;
  #pragma unroll
  for (int c = 0; c < 10; ++c){
    #pragma unroll
    for (int h = 0; h < NH; ++h){
      float wv = coef[rr][c * NH + h];
      const uint16_t* p = part + (((size_t)((b*10 + c)*NH + h))*256 + n)*256 + dc;
      uint4 v = *(const uint4*)p;
      uint32_t uu[4] = {v.x, v.y, v.z, v.w};
      #pragma unroll
      for (int q = 0; q < 4; ++q){
        acc[2*q]   = fmaf(wv, bflo(uu[q]), acc[2*q]);
        acc[2*q+1] = fmaf(wv, bfhi(uu[q]), acc[2*q+1]);
      }
    }
  }
  float* dstp = zq + ((size_t)(b*256 + n))*256 + dc;
  float4 r0 = {acc[0], acc[1], acc[2], acc[3]};
  float4 r1 = {acc[4], acc[5], acc[6], acc[7]};
  *(float4*)dstp = r0;
  *(float4*)(dstp + 4) = r1;
}

// ---------------------------------------------------------------------------
// Fallback (R2) k_zq — only if ws is tiny.
// ---------------------------------------------------------------------------
__global__ void __launch_bounds__(256)
k_zq_old(const float* __restrict__ ze, const float* __restrict__ books,
         const float* __restrict__ ws, const float* __restrict__ lpq,
         float* __restrict__ zq){
  __shared__ float ze_t[32][256];
  __shared__ float b_t[32][256];
  int B = blockIdx.x, b = B >> 3, n0 = (B & 7) << 5;
  int t = threadIdx.x, r = t >> 3, u = t & 7, lane = t & 63;
  float pq = 0.5f / fmaxf(1.0f + __expf(lpq[0]), 1e-10f);
  uint32_t ke0, ke1; tf2x32(0u, 42u, 0u, 1u, ke0, ke1);
  const float4* zsrc = (const float4*)(ze + ((size_t)(b * 256 + n0)) * 256);
  for (int q = t; q < 2048; q += 256){
    int rr = q >> 6, d4 = q & 63;
    float4 v = zsrc[q];
    *(float4*)&ze_t[rr][((d4 ^ (rr & 7)) << 2)] = v;
  }
  float4 zqa[8];
  #pragma unroll
  for (int mm = 0; mm < 8; ++mm) zqa[mm] = make_float4(0.f, 0.f, 0.f, 0.f);
  int nglob = n0 + r;
  for (int c = 0; c < 10; ++c){
    float cpc = ws[F_CP + b * 10 + c];
    uint32_t nbase = ((uint32_t)((b * 10 + c) * 256 + nglob)) << 9;
    float m = -1e30f, l = 0.f;
    float4 pz[8];
    #pragma unroll
    for (int mm = 0; mm < 8; ++mm) pz[mm] = make_float4(0.f, 0.f, 0.f, 0.f);
    for (int ci = 0; ci < 16; ++ci){
      __syncthreads();
      const float4* bsrc = (const float4*)(books + ((size_t)(c * 512 + (ci << 5))) * 256);
      for (int q = t; q < 2048; q += 256){
        int kk = q >> 6, d4 = q & 63;
        float4 v = bsrc[q];
        *(float4*)&b_t[kk][((d4 ^ (kk & 7)) << 2)] = v;
      }
      __syncthreads();
      float s0 = 0.f, s1 = 0.f, s2 = 0.f, s3 = 0.f;
      #pragma unroll 8
      for (int d4 = 0; d4 < 64; ++d4){
        float4 z  = *(const float4*)&ze_t[r][((d4 ^ (r & 7)) << 2)];
        float4 b0 = *(const float4*)&b_t[u][((d4 ^ (u & 7)) << 2)];
        float4 b1 = *(const float4*)&b_t[u + 8][((d4 ^ (u & 7)) << 2)];
        float4 b2 = *(const float4*)&b_t[u + 16][((d4 ^ (u & 7)) << 2)];
        float4 b3 = *(const float4*)&b_t[u + 24][((d4 ^ (u & 7)) << 2)];
        s0 = fmaf(z.x,b0.x,s0); s0 = fmaf(z.y,b0.y,s0); s0 = fmaf(z.z,b0.z,s0); s0 = fmaf(z.w,b0.w,s0);
        s1 = fmaf(z.x,b1.x,s1); s1 = fmaf(z.y,b1.y,s1); s1 = fmaf(z.z,b1.z,s1); s1 = fmaf(z.w,b1.w,s1);
        s2 = fmaf(z.x,b2.x,s2); s2 = fmaf(z.y,b2.y,s2); s2 = fmaf(z.z,b2.z,s2); s2 = fmaf(z.w,b2.w,s2);
        s3 = fmaf(z.x,b3.x,s3); s3 = fmaf(z.y,b3.y,s3); s3 = fmaf(z.z,b3.z,s3); s3 = fmaf(z.w,b3.w,s3);
      }
      float ss[4] = {s0, s1, s2, s3};
      float vv[4]; float cm = -1e30f;
      #pragma unroll
      for (int jj = 0; jj < 4; ++jj){
        int kg = (ci << 5) + (jj << 3) + u;
        float bk2v = ws[F_BK2 + (c << 9) + kg];
        float gg = gum_at(ke0, ke1, nbase + (uint32_t)kg);
        float v = (-pq * (bk2v - 2.0f * ss[jj]) + gg) * 2.0f;
        vv[jj] = v; cm = fmaxf(cm, v);
      }
      cm = fmaxf(cm, __shfl_xor(cm, 1));
      cm = fmaxf(cm, __shfl_xor(cm, 2));
      cm = fmaxf(cm, __shfl_xor(cm, 4));
      float mn = fmaxf(m, cm);
      float scale = __expf(m - mn);
      float csum = 0.f;
      #pragma unroll
      for (int jj = 0; jj < 4; ++jj){ vv[jj] = __expf(vv[jj] - mn); csum += vv[jj]; }
      csum += __shfl_xor(csum, 1);
      csum += __shfl_xor(csum, 2);
      csum += __shfl_xor(csum, 4);
      l = l * scale + csum;
      m = mn;
      #pragma unroll
      for (int mm = 0; mm < 8; ++mm){
        pz[mm].x *= scale; pz[mm].y *= scale; pz[mm].z *= scale; pz[mm].w *= scale;
      }
      #pragma unroll
      for (int jj = 0; jj < 4; ++jj){
        float pv = vv[jj];
        #pragma unroll
        for (int q2 = 0; q2 < 8; ++q2){
          float wk = __shfl(pv, (lane & 56) | q2, 64);
          int kl = (jj << 3) + q2;
          #pragma unroll
          for (int mm = 0; mm < 8; ++mm){
            float4 bv = *(const float4*)&b_t[kl][(((u + (mm << 3)) ^ (kl & 7)) << 2)];
            pz[mm].x = fmaf(wk, bv.x, pz[mm].x);
            pz[mm].y = fmaf(wk, bv.y, pz[mm].y);
            pz[mm].z = fmaf(wk, bv.z, pz[mm].z);
            pz[mm].w = fmaf(wk, bv.w, pz[mm].w);
          }
        }
      }
    }
    float wc = cpc / l;
    #pragma unroll
    for (int mm = 0; mm < 8; ++mm){
      zqa[mm].x = fmaf(wc, pz[mm].x, zqa[mm].x);
      zqa[mm].y = fmaf(wc, pz[mm].y, zqa[mm].y);
      zqa[mm].z = fmaf(wc, pz[mm].z, zqa[mm].z);
      zqa[mm].w = fmaf(wc, pz[mm].w, zqa[mm].w);
    }
  }
  float* dst = zq + ((size_t)(b * 256 + nglob)) * 256;
  #pragma unroll
  for (int mm = 0; mm < 8; ++mm)
    *(float4*)&dst[(u << 2) + (mm << 5)] = zqa[mm];
}

// ---------------------------------------------------------------------------
extern "C" void kernel_launch(void* const* d_in, const int* in_sizes, int n_in,
                              void* d_out, int out_size, void* d_ws, size_t ws_size,
                              hipStream_t stream){
  (void)in_sizes; (void)n_in; (void)out_size;
  const float* ze    = (const float*)d_in[0];
  const float* cl    = (const float*)d_in[1];
  const float* books = (const float*)d_in[2];
  const float* lpq   = (const float*)d_in[3];
  const float* lpqc  = (const float*)d_in[4];
  float* out  = (float*)d_out;
  float* ws   = (float*)d_ws;
  float* zq   = out;
  float* prob = out + 2097153;
  float* logp = out + 2097153 + 4194304;
  size_t wsf = ws_size / 4;

  const size_t needT2 = (size_t)O_PART + 20971520;   // NH=2 partials
  const size_t needT1 = (size_t)O_PART + 10485760;   // NH=1 partials
  const size_t needT0 = (size_t)O_M + 163840 + 10485760;  // NH=1, no M

  uint16_t* bkrm = (uint16_t*)(ws + O_BKRM);
  uint16_t* bkTg = (uint16_t*)(ws + O_BKT);

  if (wsf >= needT2 || wsf >= needT1){
    uint16_t* Mh   = (uint16_t*)(ws + O_M);
    float*    lseg = ws + O_LSE;
    uint16_t* part = (uint16_t*)(ws + O_PART);
    k_prep<<<80, 256, 0, stream>>>(books, cl, lpq, lpqc, ws, out, bkrm, bkTg);
    k_mix<<<4096, 256, 0, stream>>>(bkrm, ws, Mh);
    k_probs<1><<<512, 256, 0, stream>>>(ze, books, Mh, ws, lpq, prob, logp);
    if (wsf >= needT2){
      k_zq_mfma<8, 2><<<1280, 512, 0, stream>>>(ze, bkrm, bkTg, ws, lpq, part, lseg);
      k_comb<2><<<1024, 256, 0, stream>>>(part, lseg, ws, zq);
    } else {
      k_zq_mfma<16, 1><<<640, 512, 0, stream>>>(ze, bkrm, bkTg, ws, lpq, part, lseg);
      k_comb<1><<<1024, 256, 0, stream>>>(part, lseg, ws, zq);
    }
  } else if (wsf >= needT0){
    float*    lseg = ws + O_M;
    uint16_t* part = (uint16_t*)(ws + O_M + 163840);
    k_prep<<<80, 256, 0, stream>>>(books, cl, lpq, lpqc, ws, out, bkrm, bkTg);
    k_probs<0><<<512, 256, 0, stream>>>(ze, books, nullptr, ws, lpq, prob, logp);
    k_zq_mfma<16, 1><<<640, 512, 0, stream>>>(ze, bkrm, bkTg, ws, lpq, part, lseg);
    k_comb<1><<<1024, 256, 0, stream>>>(part, lseg, ws, zq);
  } else {
    k_prep<<<80, 256, 0, stream>>>(books, cl, lpq, lpqc, ws, out, bkrm, bkTg);
    k_probs<0><<<512, 256, 0, stream>>>(ze, books, nullptr, ws, lpq, prob, logp);
    k_zq_old<<<256, 256, 0, stream>>>(ze, books, ws, lpq, zq);
  }
}